// Round 1
// baseline (728.829 us; speedup 1.0000x reference)
//
#include <hip/hip_runtime.h>

// Problem constants (fixed by the reference)
#define CS     128   // chunk size
#define EDIM   256   // embedding dim
#define NBATCH 2
#define TLEN   8192
#define NCHUNK 64    // TLEN / CS
#define LEXT   1024  // K * CS
#define KSEL   7     // K - 1

// ---------------------------------------------------------------------------
// Stage A: reciprocal row norms  rnorm[b*T + t] = 1 / (||x_row|| + 1e-6)
// one wave per row (64 lanes x float4 = 256 floats)
// ---------------------------------------------------------------------------
__global__ __launch_bounds__(256) void rnorm_kernel(const float* __restrict__ x,
                                                    float* __restrict__ rnorm) {
    int row  = blockIdx.x * 4 + (threadIdx.x >> 6);
    int lane = threadIdx.x & 63;
    const float4 v = ((const float4*)(x + (size_t)row * EDIM))[lane];
    float s = v.x * v.x + v.y * v.y + v.z * v.z + v.w * v.w;
#pragma unroll
    for (int off = 1; off < 64; off <<= 1) s += __shfl_xor(s, off);
    if (lane == 0) rnorm[row] = 1.0f / (sqrtf(s) + 1e-6f);
}

// ---------------------------------------------------------------------------
// Stage B: fused cosine-sim GEMM + rowmax + sum -> scores[b,i,j], j < i
// One workgroup per (b,i,j). 256 threads as 16x16, 8x8 register tile each.
// LDS tiles transposed: As[e][c], Bs[e][d]; +4 pad keeps b128 alignment and
// makes the transpose scalar-writes 2-way (free) instead of 8-way.
// ---------------------------------------------------------------------------
__global__ __launch_bounds__(256) void scores_kernel(const float* __restrict__ x,
                                                     const float* __restrict__ rnorm,
                                                     float* __restrict__ scores) {
    const int j = blockIdx.x, i = blockIdx.y, b = blockIdx.z;
    if (j >= i) return;  // causal: only j < i used downstream

    __shared__ float As[32][132];
    __shared__ float Bs[32][132];
    __shared__ double red[16];

    const int tid = threadIdx.x;
    const int tx = tid & 15, ty = tid >> 4;

    float acc[8][8];
#pragma unroll
    for (int c = 0; c < 8; ++c)
#pragma unroll
        for (int d = 0; d < 8; ++d) acc[c][d] = 0.0f;

    const int rowi = b * TLEN + i * CS;
    const int rowj = b * TLEN + j * CS;
    const int c0 = tid >> 3;         // 0..31
    const int eq = (tid & 7) << 2;   // 0,4,...,28

    for (int es = 0; es < EDIM; es += 32) {
#pragma unroll
        for (int p = 0; p < 4; ++p) {
            int c = c0 + p * 32;
            float4 va = *(const float4*)(x + (size_t)(rowi + c) * EDIM + es + eq);
            float  ra = rnorm[rowi + c];
            As[eq + 0][c] = va.x * ra; As[eq + 1][c] = va.y * ra;
            As[eq + 2][c] = va.z * ra; As[eq + 3][c] = va.w * ra;
            float4 vb = *(const float4*)(x + (size_t)(rowj + c) * EDIM + es + eq);
            float  rb = rnorm[rowj + c];
            Bs[eq + 0][c] = vb.x * rb; Bs[eq + 1][c] = vb.y * rb;
            Bs[eq + 2][c] = vb.z * rb; Bs[eq + 3][c] = vb.w * rb;
        }
        __syncthreads();
#pragma unroll
        for (int e = 0; e < 32; ++e) {
            float4 a0 = *(const float4*)&As[e][ty * 8];
            float4 a1 = *(const float4*)&As[e][ty * 8 + 4];
            float4 b0 = *(const float4*)&Bs[e][tx * 8];
            float4 b1 = *(const float4*)&Bs[e][tx * 8 + 4];
            float a[8]  = {a0.x, a0.y, a0.z, a0.w, a1.x, a1.y, a1.z, a1.w};
            float bb[8] = {b0.x, b0.y, b0.z, b0.w, b1.x, b1.y, b1.z, b1.w};
#pragma unroll
            for (int c = 0; c < 8; ++c)
#pragma unroll
                for (int d = 0; d < 8; ++d)
                    acc[c][d] = fmaf(a[c], bb[d], acc[c][d]);
        }
        __syncthreads();
    }

    // rowmax over d (this thread's 8 d's), then across the 16 tx lanes
    float m[8];
#pragma unroll
    for (int c = 0; c < 8; ++c) {
        float mm = acc[c][0];
#pragma unroll
        for (int d = 1; d < 8; ++d) mm = fmaxf(mm, acc[c][d]);
        m[c] = mm;
    }
#pragma unroll
    for (int off = 1; off < 16; off <<= 1)
#pragma unroll
        for (int c = 0; c < 8; ++c) m[c] = fmaxf(m[c], __shfl_xor(m[c], off));

    // sum over c in double: keeps score error ~1e-6 so top-k ranks are stable
    double s = 0.0;
#pragma unroll
    for (int c = 0; c < 8; ++c) s += (double)m[c];
    if (tx == 0) red[ty] = s;
    __syncthreads();
    if (tid == 0) {
        double t = 0.0;
#pragma unroll
        for (int k = 0; k < 16; ++k) t += red[k];
        scores[(b * NCHUNK + i) * NCHUNK + j] = (float)t;
    }
}

// ---------------------------------------------------------------------------
// Stage C: top-7 selection + weights + left-pad arrangement.
// One thread per (b,i); serial over <=63 candidates (tiny).
// ext slot s in [0,7): chunk index (or -1) and weight, in ext layout order.
// ---------------------------------------------------------------------------
__global__ void topk_kernel(const float* __restrict__ scores,
                            int* __restrict__ ext_idx,
                            float* __restrict__ ext_w) {
    int tid = threadIdx.x;
    if (tid >= NBATCH * NCHUNK) return;
    int b = tid >> 6, i = tid & 63;
    const float* srow = scores + (b * NCHUNK + i) * NCHUNK;

    int nsel = i < KSEL ? i : KSEL;
    float vals[KSEL];
    int   idxs[KSEL];
    unsigned long long used = 0ull;
    for (int s = 0; s < nsel; ++s) {
        float best = -3.0e38f;
        int   bj = 0;
        for (int jj = 0; jj < i; ++jj) {
            if ((used >> jj) & 1ull) continue;
            float v = srow[jj];
            if (v > best) { best = v; bj = jj; }  // strict >: ties pick lowest j (matches lax.top_k)
        }
        used |= 1ull << bj;
        vals[s] = best;
        idxs[s] = bj;
    }
    float vmin = (nsel > 0) ? vals[nsel - 1] : 0.0f;
    float inv  = 1.0f / (vmin + 1e-6f);
    int shift  = KSEL - nsel;  // == max(0, 7 - i)
    for (int s = 0; s < KSEL; ++s) {
        int t = s - shift;
        int o = (b * NCHUNK + i) * KSEL + s;
        if (t >= 0) { ext_idx[o] = idxs[t]; ext_w[o] = vals[t] * inv; }
        else        { ext_idx[o] = -1;      ext_w[o] = 0.0f; }
    }
}

// ---------------------------------------------------------------------------
// Stage D: out[b,n] = down_proj @ ext(b,n) + chunk(b,n)
// Grid (ehalf, n, b); 128x128 out tile, K = 1024 in 32-slices. Each 32-slice
// lies inside one ext slot, so the gather index/weight is uniform per slice.
// ---------------------------------------------------------------------------
__global__ __launch_bounds__(256) void out_kernel(const float* __restrict__ x,
                                                  const float* __restrict__ dp,
                                                  const int* __restrict__ ext_idx,
                                                  const float* __restrict__ ext_w,
                                                  float* __restrict__ out) {
    const int eh = blockIdx.x, n = blockIdx.y, b = blockIdx.z;
    __shared__ float As[32][132];
    __shared__ float Bs[32][132];

    const int tid = threadIdx.x;
    const int tx = tid & 15, ty = tid >> 4;
    const int e0 = eh * 128;

    float acc[8][8];
#pragma unroll
    for (int c = 0; c < 8; ++c)
#pragma unroll
        for (int d = 0; d < 8; ++d) acc[c][d] = 0.0f;

    const int c0  = tid >> 3;          // 0..31 (A loader)
    const int lq  = (tid & 7) << 2;    // 0..28 (A loader)
    const int er  = (tid & 31) << 2;   // 0..124 (B loader, e within tile)
    const int r0t = tid >> 5;          // 0..7   (B loader, row within pass)

    for (int ls = 0; ls < LEXT; ls += 32) {
        // A tile (transposed): As[l][c] = dp[c][ls+l]
#pragma unroll
        for (int p = 0; p < 4; ++p) {
            int c = c0 + p * 32;
            float4 v = *(const float4*)(dp + (size_t)c * LEXT + ls + lq);
            As[lq + 0][c] = v.x; As[lq + 1][c] = v.y;
            As[lq + 2][c] = v.z; As[lq + 3][c] = v.w;
        }
        // B tile: Bs[l][e] = w_slot * x[b, j_slot*CS + r, e0+e]
        int slot = ls >> 7;
        int r0   = ls & 127;
        int jj; float w;
        if (slot < KSEL) {
            jj = ext_idx[(b * NCHUNK + n) * KSEL + slot];
            w  = ext_w [(b * NCHUNK + n) * KSEL + slot];
        } else { jj = n; w = 1.0f; }
        if (jj >= 0) {
#pragma unroll
            for (int p = 0; p < 4; ++p) {
                int rr = r0t + p * 8;
                float4 v = *(const float4*)(x + (size_t)(b * TLEN + jj * CS + r0 + rr) * EDIM + e0 + er);
                v.x *= w; v.y *= w; v.z *= w; v.w *= w;
                *(float4*)&Bs[rr][er] = v;
            }
        } else {
            float4 z = {0.0f, 0.0f, 0.0f, 0.0f};
#pragma unroll
            for (int p = 0; p < 4; ++p) *(float4*)&Bs[r0t + p * 8][er] = z;
        }
        __syncthreads();
#pragma unroll
        for (int l = 0; l < 32; ++l) {
            float4 a0 = *(const float4*)&As[l][ty * 8];
            float4 a1 = *(const float4*)&As[l][ty * 8 + 4];
            float4 b0 = *(const float4*)&Bs[l][tx * 8];
            float4 b1 = *(const float4*)&Bs[l][tx * 8 + 4];
            float a[8]  = {a0.x, a0.y, a0.z, a0.w, a1.x, a1.y, a1.z, a1.w};
            float bb[8] = {b0.x, b0.y, b0.z, b0.w, b1.x, b1.y, b1.z, b1.w};
#pragma unroll
            for (int c = 0; c < 8; ++c)
#pragma unroll
                for (int d = 0; d < 8; ++d)
                    acc[c][d] = fmaf(a[c], bb[d], acc[c][d]);
        }
        __syncthreads();
    }

    // epilogue: + chunk bias, store
#pragma unroll
    for (int cc = 0; cc < 8; ++cc) {
        int row = b * TLEN + n * CS + ty * 8 + cc;
        const float* bp = x + (size_t)row * EDIM + e0 + tx * 8;
        float4 b0 = *(const float4*)bp;
        float4 b1 = *(const float4*)(bp + 4);
        float4 o0, o1;
        o0.x = acc[cc][0] + b0.x; o0.y = acc[cc][1] + b0.y;
        o0.z = acc[cc][2] + b0.z; o0.w = acc[cc][3] + b0.w;
        o1.x = acc[cc][4] + b1.x; o1.y = acc[cc][5] + b1.y;
        o1.z = acc[cc][6] + b1.z; o1.w = acc[cc][7] + b1.w;
        float* op = out + (size_t)row * EDIM + e0 + tx * 8;
        *(float4*)op       = o0;
        *(float4*)(op + 4) = o1;
    }
}

// ---------------------------------------------------------------------------
extern "C" void kernel_launch(void* const* d_in, const int* in_sizes, int n_in,
                              void* d_out, int out_size, void* d_ws, size_t ws_size,
                              hipStream_t stream) {
    const float* x  = (const float*)d_in[0];   // [2, 8192, 256] fp32
    const float* dp = (const float*)d_in[1];   // [128, 1024] fp32
    float* out = (float*)d_out;                // [2, 8192, 256] fp32

    char* ws = (char*)d_ws;
    float* rnorm   = (float*)ws;                          // 16384 floats (64 KB)
    float* scores  = (float*)(ws + 65536);                // 8192 floats  (32 KB)
    int*   ext_idx = (int*)  (ws + 65536 + 32768);        // 896 ints
    float* ext_w   = (float*)(ws + 65536 + 32768 + 4096); // 896 floats

    rnorm_kernel <<<dim3(NBATCH * TLEN / 4), 256, 0, stream>>>(x, rnorm);
    scores_kernel<<<dim3(NCHUNK, NCHUNK, NBATCH), 256, 0, stream>>>(x, rnorm, scores);
    topk_kernel  <<<1, 128, 0, stream>>>(scores, ext_idx, ext_w);
    out_kernel   <<<dim3(2, NCHUNK, NBATCH), 256, 0, stream>>>(x, dp, ext_idx, ext_w, out);
}

// Round 2
// 368.834 us; speedup vs baseline: 1.9760x; 1.9760x over previous
//
#include <hip/hip_runtime.h>
#include <hip/hip_bf16.h>

// Problem constants (fixed by the reference)
#define CS     128
#define EDIM   256
#define NBATCH 2
#define TLEN   8192
#define NCHUNK 64
#define LEXT   1024
#define KSEL   7

typedef __attribute__((ext_vector_type(8))) short   short8;   // 8 bf16 = 4 VGPR (MFMA A/B frag)
typedef __attribute__((ext_vector_type(4))) float   floatx4;  // MFMA C/D frag

__device__ inline short bf16_of(float f) {
    __hip_bfloat16 h = __float2bfloat16(f);
    return *(short*)&h;
}
__device__ inline float f_of_bf16(short s) {
    __hip_bfloat16 h = *(__hip_bfloat16*)&s;
    return __bfloat162float(h);
}

// async global->LDS, 16B per lane; LDS dest = wave-uniform base + lane*16
__device__ inline void gl_lds16(const void* g, void* l) {
    __builtin_amdgcn_global_load_lds(
        (const __attribute__((address_space(1))) unsigned int*)g,
        (__attribute__((address_space(3))) unsigned int*)l, 16, 0, 0);
}

// ---------------------------------------------------------------------------
// Stage A: normalize rows and split into bf16 hi/lo:  cn = x / (||x||+eps)
// hi = bf16(cn), lo = bf16(cn - hi). One wave per row.
// ---------------------------------------------------------------------------
__global__ __launch_bounds__(256) void normsplit_kernel(const float* __restrict__ x,
                                                        short* __restrict__ cn_hi,
                                                        short* __restrict__ cn_lo) {
    int row  = blockIdx.x * 4 + (threadIdx.x >> 6);
    int lane = threadIdx.x & 63;
    const float4 v = ((const float4*)(x + (size_t)row * EDIM))[lane];
    float s = v.x * v.x + v.y * v.y + v.z * v.z + v.w * v.w;
#pragma unroll
    for (int off = 1; off < 64; off <<= 1) s += __shfl_xor(s, off);
    float r = 1.0f / (sqrtf(s) + 1e-6f);

    float c[4] = {v.x * r, v.y * r, v.z * r, v.w * r};
    short hs[4], ls[4];
#pragma unroll
    for (int q = 0; q < 4; ++q) {
        hs[q] = bf16_of(c[q]);
        ls[q] = bf16_of(c[q] - f_of_bf16(hs[q]));
    }
    size_t o = (size_t)row * EDIM + lane * 4;
    *(short4*)(cn_hi + o) = make_short4(hs[0], hs[1], hs[2], hs[3]);
    *(short4*)(cn_lo + o) = make_short4(ls[0], ls[1], ls[2], ls[3]);
}

// ---------------------------------------------------------------------------
// Stage B: split-bf16 MFMA cosine-sim GEMM + rowmax + sum -> scores[b,i,j]
// Compact triangular grid: block p -> (i,j), j<i. 4 waves in 2x2, each 64x64.
// sims ~= Ah*Bh + Ah*Bl + Al*Bh  (lo*lo dropped: ~2^-16 rel err)
// LDS tiles: [4][128 rows][32 bf16] (Ahi,Alo,Bhi,Blo), unpadded stride 64B ->
// frag ds_read_b128 hits all 32 banks uniformly (bank = 16*(row&1)+4q+w).
// ---------------------------------------------------------------------------
__global__ __launch_bounds__(256) void scores_mfma(const short* __restrict__ cn_hi,
                                                   const short* __restrict__ cn_lo,
                                                   float* __restrict__ scores) {
    __shared__ short  tiles[4][128 * 32];   // 32 KB
    __shared__ float  redbuf[2][128];
    __shared__ double red2[2];

    const int p = blockIdx.x, b = blockIdx.y;
    int i = (int)((1.0f + sqrtf(1.0f + 8.0f * (float)p)) * 0.5f);
    while (i * (i - 1) / 2 > p) --i;
    while (i * (i + 1) / 2 <= p) ++i;
    const int j = p - i * (i - 1) / 2;

    const int tid  = threadIdx.x;
    const int w    = tid >> 6, lane = tid & 63;
    const int wr   = w >> 1, wc = w & 1;
    const int quad = lane >> 4, l15 = lane & 15;

    // staging role: wave w loads matrix w: 0=Ahi 1=Alo 2=Bhi 3=Blo
    const short* sarr  = (w & 1) ? cn_lo : cn_hi;
    const size_t sbase = ((size_t)b * TLEN + ((w >> 1) ? j : i) * CS) * EDIM;
    const int rr  = lane >> 2;        // row within 16-row group
    const int c16 = (lane & 3) * 8;   // bf16 offset within 64B row-slice

    floatx4 acc[4][4];
#pragma unroll
    for (int rt = 0; rt < 4; ++rt)
#pragma unroll
        for (int ct = 0; ct < 4; ++ct) acc[rt][ct] = (floatx4){0.f, 0.f, 0.f, 0.f};

    for (int ks = 0; ks < 8; ++ks) {
        const short* gsrc = sarr + sbase + ks * 32 + c16;
        short* ldst = &tiles[w][0];
#pragma unroll
        for (int t = 0; t < 8; ++t)
            gl_lds16(gsrc + (size_t)(16 * t + rr) * EDIM, ldst + t * 512);
        __syncthreads();   // own vmcnt(0) drain + barrier: tiles complete

        short8 bh[4], bl[4];
#pragma unroll
        for (int ct = 0; ct < 4; ++ct) {
            int r = wc * 64 + ct * 16 + l15;
            bh[ct] = *(const short8*)&tiles[2][r * 32 + quad * 8];
            bl[ct] = *(const short8*)&tiles[3][r * 32 + quad * 8];
        }
#pragma unroll
        for (int rt = 0; rt < 4; ++rt) {
            int r = wr * 64 + rt * 16 + l15;
            short8 ah = *(const short8*)&tiles[0][r * 32 + quad * 8];
            short8 al = *(const short8*)&tiles[1][r * 32 + quad * 8];
#pragma unroll
            for (int ct = 0; ct < 4; ++ct) {
                acc[rt][ct] = __builtin_amdgcn_mfma_f32_16x16x32_bf16(ah, bh[ct], acc[rt][ct], 0, 0, 0);
                acc[rt][ct] = __builtin_amdgcn_mfma_f32_16x16x32_bf16(ah, bl[ct], acc[rt][ct], 0, 0, 0);
                acc[rt][ct] = __builtin_amdgcn_mfma_f32_16x16x32_bf16(al, bh[ct], acc[rt][ct], 0, 0, 0);
            }
        }
        __syncthreads();   // protect tiles before next kstep's staging
    }

    // epilogue: lane holds D[row = rt*16 + quad*4 + reg][col = ct*16 + l15]
    // rowmax over this wave's 64 cols, butterfly across l15, stash per col-half
#pragma unroll
    for (int rt = 0; rt < 4; ++rt) {
        float m[4];
#pragma unroll
        for (int reg = 0; reg < 4; ++reg) {
            float mm = acc[rt][0][reg];
#pragma unroll
            for (int ct = 1; ct < 4; ++ct) mm = fmaxf(mm, acc[rt][ct][reg]);
            m[reg] = mm;
        }
#pragma unroll
        for (int off = 1; off < 16; off <<= 1)
#pragma unroll
            for (int reg = 0; reg < 4; ++reg) m[reg] = fmaxf(m[reg], __shfl_xor(m[reg], off));
        if (l15 == 0) {
#pragma unroll
            for (int reg = 0; reg < 4; ++reg)
                redbuf[wc][wr * 64 + rt * 16 + quad * 4 + reg] = m[reg];
        }
    }
    __syncthreads();

    double part = 0.0;
    if (tid < 128) part = (double)fmaxf(redbuf[0][tid], redbuf[1][tid]);
#pragma unroll
    for (int off = 1; off < 64; off <<= 1) part += __shfl_xor(part, off);
    if (lane == 0 && w < 2) red2[w] = part;
    __syncthreads();
    if (tid == 0) scores[(b * NCHUNK + i) * NCHUNK + j] = (float)(red2[0] + red2[1]);
}

// ---------------------------------------------------------------------------
// Stage C: top-7 selection + weights + left-pad arrangement (tiny, serial)
// ---------------------------------------------------------------------------
__global__ void topk_kernel(const float* __restrict__ scores,
                            int* __restrict__ ext_idx,
                            float* __restrict__ ext_w) {
    int tid = threadIdx.x;
    if (tid >= NBATCH * NCHUNK) return;
    int b = tid >> 6, i = tid & 63;
    const float* srow = scores + (b * NCHUNK + i) * NCHUNK;

    int nsel = i < KSEL ? i : KSEL;
    float vals[KSEL];
    int   idxs[KSEL];
    unsigned long long used = 0ull;
    for (int s = 0; s < nsel; ++s) {
        float best = -3.0e38f;
        int   bj = 0;
        for (int jj = 0; jj < i; ++jj) {
            if ((used >> jj) & 1ull) continue;
            float v = srow[jj];
            if (v > best) { best = v; bj = jj; }
        }
        used |= 1ull << bj;
        vals[s] = best;
        idxs[s] = bj;
    }
    float vmin = (nsel > 0) ? vals[nsel - 1] : 0.0f;
    float inv  = 1.0f / (vmin + 1e-6f);
    int shift  = KSEL - nsel;
    for (int s = 0; s < KSEL; ++s) {
        int t = s - shift;
        int o = (b * NCHUNK + i) * KSEL + s;
        if (t >= 0) { ext_idx[o] = idxs[t]; ext_w[o] = vals[t] * inv; }
        else        { ext_idx[o] = -1;      ext_w[o] = 0.0f; }
    }
}

// ---------------------------------------------------------------------------
// Stage D: out[b,n] = down_proj @ ext(b,n) + chunk(b,n)  (fp32 VALU GEMM)
// ---------------------------------------------------------------------------
__global__ __launch_bounds__(256) void out_kernel(const float* __restrict__ x,
                                                  const float* __restrict__ dp,
                                                  const int* __restrict__ ext_idx,
                                                  const float* __restrict__ ext_w,
                                                  float* __restrict__ out) {
    const int eh = blockIdx.x, n = blockIdx.y, b = blockIdx.z;
    __shared__ float As[32][132];
    __shared__ float Bs[32][132];

    const int tid = threadIdx.x;
    const int tx = tid & 15, ty = tid >> 4;
    const int e0 = eh * 128;

    float acc[8][8];
#pragma unroll
    for (int c = 0; c < 8; ++c)
#pragma unroll
        for (int d = 0; d < 8; ++d) acc[c][d] = 0.0f;

    const int c0  = tid >> 3;
    const int lq  = (tid & 7) << 2;
    const int er  = (tid & 31) << 2;
    const int r0t = tid >> 5;

    for (int ls = 0; ls < LEXT; ls += 32) {
#pragma unroll
        for (int p = 0; p < 4; ++p) {
            int c = c0 + p * 32;
            float4 v = *(const float4*)(dp + (size_t)c * LEXT + ls + lq);
            As[lq + 0][c] = v.x; As[lq + 1][c] = v.y;
            As[lq + 2][c] = v.z; As[lq + 3][c] = v.w;
        }
        int slot = ls >> 7;
        int r0   = ls & 127;
        int jj; float w;
        if (slot < KSEL) {
            jj = ext_idx[(b * NCHUNK + n) * KSEL + slot];
            w  = ext_w [(b * NCHUNK + n) * KSEL + slot];
        } else { jj = n; w = 1.0f; }
        if (jj >= 0) {
#pragma unroll
            for (int p = 0; p < 4; ++p) {
                int rr = r0t + p * 8;
                float4 v = *(const float4*)(x + (size_t)(b * TLEN + jj * CS + r0 + rr) * EDIM + e0 + er);
                v.x *= w; v.y *= w; v.z *= w; v.w *= w;
                *(float4*)&Bs[rr][er] = v;
            }
        } else {
            float4 z = {0.0f, 0.0f, 0.0f, 0.0f};
#pragma unroll
            for (int p = 0; p < 4; ++p) *(float4*)&Bs[r0t + p * 8][er] = z;
        }
        __syncthreads();
#pragma unroll
        for (int l = 0; l < 32; ++l) {
            float4 a0 = *(const float4*)&As[l][ty * 8];
            float4 a1 = *(const float4*)&As[l][ty * 8 + 4];
            float4 b0 = *(const float4*)&Bs[l][tx * 8];
            float4 b1 = *(const float4*)&Bs[l][tx * 8 + 4];
            float a[8]  = {a0.x, a0.y, a0.z, a0.w, a1.x, a1.y, a1.z, a1.w};
            float bb[8] = {b0.x, b0.y, b0.z, b0.w, b1.x, b1.y, b1.z, b1.w};
#pragma unroll
            for (int c = 0; c < 8; ++c)
#pragma unroll
                for (int d = 0; d < 8; ++d)
                    acc[c][d] = fmaf(a[c], bb[d], acc[c][d]);
        }
        __syncthreads();
    }

#pragma unroll
    for (int cc = 0; cc < 8; ++cc) {
        int row = b * TLEN + n * CS + ty * 8 + cc;
        const float* bp = x + (size_t)row * EDIM + e0 + tx * 8;
        float4 b0 = *(const float4*)bp;
        float4 b1 = *(const float4*)(bp + 4);
        float4 o0, o1;
        o0.x = acc[cc][0] + b0.x; o0.y = acc[cc][1] + b0.y;
        o0.z = acc[cc][2] + b0.z; o0.w = acc[cc][3] + b0.w;
        o1.x = acc[cc][4] + b1.x; o1.y = acc[cc][5] + b1.y;
        o1.z = acc[cc][6] + b1.z; o1.w = acc[cc][7] + b1.w;
        float* op = out + (size_t)row * EDIM + e0 + tx * 8;
        *(float4*)op       = o0;
        *(float4*)(op + 4) = o1;
    }
}

// ---------------------------------------------------------------------------
extern "C" void kernel_launch(void* const* d_in, const int* in_sizes, int n_in,
                              void* d_out, int out_size, void* d_ws, size_t ws_size,
                              hipStream_t stream) {
    const float* x  = (const float*)d_in[0];   // [2, 8192, 256] fp32
    const float* dp = (const float*)d_in[1];   // [128, 1024] fp32
    float* out = (float*)d_out;

    char* ws = (char*)d_ws;
    short* cn_hi  = (short*)ws;                                  // 8 MB
    short* cn_lo  = (short*)(ws + 8388608);                      // 8 MB
    float* scores = (float*)(ws + 16777216);                     // 32 KB
    int*   ext_idx = (int*)  (ws + 16777216 + 32768);
    float* ext_w   = (float*)(ws + 16777216 + 32768 + 4096);

    normsplit_kernel<<<dim3(NBATCH * TLEN / 4), 256, 0, stream>>>(x, cn_hi, cn_lo);
    scores_mfma     <<<dim3(NCHUNK * (NCHUNK - 1) / 2, NBATCH), 256, 0, stream>>>(cn_hi, cn_lo, scores);
    topk_kernel     <<<1, 128, 0, stream>>>(scores, ext_idx, ext_w);
    out_kernel      <<<dim3(2, NCHUNK, NBATCH), 256, 0, stream>>>(x, dp, ext_idx, ext_w, out);
}

// Round 3
// 292.744 us; speedup vs baseline: 2.4896x; 1.2599x over previous
//
#include <hip/hip_runtime.h>
#include <hip/hip_bf16.h>

// Problem constants (fixed by the reference)
#define CS     128
#define EDIM   256
#define NBATCH 2
#define TLEN   8192
#define NCHUNK 64
#define LEXT   1024
#define KSEL   7

typedef __attribute__((ext_vector_type(8))) short   short8;   // 8 bf16 = 4 VGPR (MFMA A/B frag)
typedef __attribute__((ext_vector_type(4))) float   floatx4;  // MFMA C/D frag

__device__ inline short bf16_of(float f) {
    __hip_bfloat16 h = __float2bfloat16(f);
    return *(short*)&h;
}
__device__ inline float f_of_bf16(short s) {
    __hip_bfloat16 h = *(__hip_bfloat16*)&s;
    return __bfloat162float(h);
}

// async global->LDS, 16B per lane; LDS dest = wave-uniform base + lane*16
__device__ inline void gl_lds16(const void* g, void* l) {
    __builtin_amdgcn_global_load_lds(
        (const __attribute__((address_space(1))) unsigned int*)g,
        (__attribute__((address_space(3))) unsigned int*)l, 16, 0, 0);
}

// ---------------------------------------------------------------------------
// Stage A1: normalize rows, split to bf16 hi/lo (for scores). One wave/row.
// ---------------------------------------------------------------------------
__global__ __launch_bounds__(256) void normsplit_kernel(const float* __restrict__ x,
                                                        short* __restrict__ cn_hi,
                                                        short* __restrict__ cn_lo) {
    int row  = blockIdx.x * 4 + (threadIdx.x >> 6);
    int lane = threadIdx.x & 63;
    const float4 v = ((const float4*)(x + (size_t)row * EDIM))[lane];
    float s = v.x * v.x + v.y * v.y + v.z * v.z + v.w * v.w;
#pragma unroll
    for (int off = 1; off < 64; off <<= 1) s += __shfl_xor(s, off);
    float r = 1.0f / (sqrtf(s) + 1e-6f);

    float c[4] = {v.x * r, v.y * r, v.z * r, v.w * r};
    short hs[4], ls[4];
#pragma unroll
    for (int q = 0; q < 4; ++q) {
        hs[q] = bf16_of(c[q]);
        ls[q] = bf16_of(c[q] - f_of_bf16(hs[q]));
    }
    size_t o = (size_t)row * EDIM + lane * 4;
    *(short4*)(cn_hi + o) = make_short4(hs[0], hs[1], hs[2], hs[3]);
    *(short4*)(cn_lo + o) = make_short4(ls[0], ls[1], ls[2], ls[3]);
}

// ---------------------------------------------------------------------------
// Stage A2: split down_proj to bf16 hi/lo (131072 elems, float4/thread)
// ---------------------------------------------------------------------------
__global__ __launch_bounds__(256) void dp_split_kernel(const float* __restrict__ dp,
                                                       short* __restrict__ dph,
                                                       short* __restrict__ dpl) {
    int idx = (blockIdx.x * 256 + threadIdx.x) * 4;
    float4 v = *(const float4*)(dp + idx);
    float c[4] = {v.x, v.y, v.z, v.w};
    short hs[4], ls[4];
#pragma unroll
    for (int q = 0; q < 4; ++q) {
        hs[q] = bf16_of(c[q]);
        ls[q] = bf16_of(c[q] - f_of_bf16(hs[q]));
    }
    *(short4*)(dph + idx) = make_short4(hs[0], hs[1], hs[2], hs[3]);
    *(short4*)(dpl + idx) = make_short4(ls[0], ls[1], ls[2], ls[3]);
}

// ---------------------------------------------------------------------------
// Stage A3: transpose x to [b][e][t] and split bf16 hi/lo (for out B-operand;
// K-dim t must be contiguous for MFMA B fragments). 64x64 LDS tile transpose.
// ---------------------------------------------------------------------------
__global__ __launch_bounds__(256) void xt_split_kernel(const float* __restrict__ x,
                                                       short* __restrict__ xth,
                                                       short* __restrict__ xtl) {
    __shared__ float tile[64][68];   // 68: b128-aligned rows, breaks pow2 stride
    const int e0 = blockIdx.x * 64, t0 = blockIdx.y * 64, b = blockIdx.z;
    const int tid = threadIdx.x;
    const int cr = tid >> 4, cc = (tid & 15) * 4;
#pragma unroll
    for (int p = 0; p < 4; ++p) {
        int r = cr + p * 16;
        float4 v = *(const float4*)(x + ((size_t)(b * TLEN + t0 + r)) * EDIM + e0 + cc);
        *(float4*)&tile[r][cc] = v;
    }
    __syncthreads();
    const int e = tid >> 2, toff = (tid & 3) * 16;
    short hs[16], ls[16];
#pragma unroll
    for (int q = 0; q < 16; ++q) {
        float f = tile[toff + q][e];
        hs[q] = bf16_of(f);
        ls[q] = bf16_of(f - f_of_bf16(hs[q]));
    }
    size_t o = ((size_t)(b * EDIM + e0 + e)) * TLEN + t0 + toff;
#pragma unroll
    for (int q4 = 0; q4 < 4; ++q4) {
        *(short4*)(xth + o + q4 * 4) = make_short4(hs[q4*4], hs[q4*4+1], hs[q4*4+2], hs[q4*4+3]);
        *(short4*)(xtl + o + q4 * 4) = make_short4(ls[q4*4], ls[q4*4+1], ls[q4*4+2], ls[q4*4+3]);
    }
}

// ---------------------------------------------------------------------------
// Stage B: split-bf16 MFMA cosine-sim GEMM + rowmax + sum -> scores[b,i,j]
// (unchanged from round 2 — passed at absmax 0.03125)
// ---------------------------------------------------------------------------
__global__ __launch_bounds__(256) void scores_mfma(const short* __restrict__ cn_hi,
                                                   const short* __restrict__ cn_lo,
                                                   float* __restrict__ scores) {
    __shared__ short  tiles[4][128 * 32];   // 32 KB
    __shared__ float  redbuf[2][128];
    __shared__ double red2[2];

    const int p = blockIdx.x, b = blockIdx.y;
    int i = (int)((1.0f + sqrtf(1.0f + 8.0f * (float)p)) * 0.5f);
    while (i * (i - 1) / 2 > p) --i;
    while (i * (i + 1) / 2 <= p) ++i;
    const int j = p - i * (i - 1) / 2;

    const int tid  = threadIdx.x;
    const int w    = tid >> 6, lane = tid & 63;
    const int wr   = w >> 1, wc = w & 1;
    const int quad = lane >> 4, l15 = lane & 15;

    const short* sarr  = (w & 1) ? cn_lo : cn_hi;
    const size_t sbase = ((size_t)b * TLEN + ((w >> 1) ? j : i) * CS) * EDIM;
    const int rr  = lane >> 2;
    const int c16 = (lane & 3) * 8;

    floatx4 acc[4][4];
#pragma unroll
    for (int rt = 0; rt < 4; ++rt)
#pragma unroll
        for (int ct = 0; ct < 4; ++ct) acc[rt][ct] = (floatx4){0.f, 0.f, 0.f, 0.f};

    for (int ks = 0; ks < 8; ++ks) {
        const short* gsrc = sarr + sbase + ks * 32 + c16;
        short* ldst = &tiles[w][0];
#pragma unroll
        for (int t = 0; t < 8; ++t)
            gl_lds16(gsrc + (size_t)(16 * t + rr) * EDIM, ldst + t * 512);
        __syncthreads();

        short8 bh[4], bl[4];
#pragma unroll
        for (int ct = 0; ct < 4; ++ct) {
            int r = wc * 64 + ct * 16 + l15;
            bh[ct] = *(const short8*)&tiles[2][r * 32 + quad * 8];
            bl[ct] = *(const short8*)&tiles[3][r * 32 + quad * 8];
        }
#pragma unroll
        for (int rt = 0; rt < 4; ++rt) {
            int r = wr * 64 + rt * 16 + l15;
            short8 ah = *(const short8*)&tiles[0][r * 32 + quad * 8];
            short8 al = *(const short8*)&tiles[1][r * 32 + quad * 8];
#pragma unroll
            for (int ct = 0; ct < 4; ++ct) {
                acc[rt][ct] = __builtin_amdgcn_mfma_f32_16x16x32_bf16(ah, bh[ct], acc[rt][ct], 0, 0, 0);
                acc[rt][ct] = __builtin_amdgcn_mfma_f32_16x16x32_bf16(ah, bl[ct], acc[rt][ct], 0, 0, 0);
                acc[rt][ct] = __builtin_amdgcn_mfma_f32_16x16x32_bf16(al, bh[ct], acc[rt][ct], 0, 0, 0);
            }
        }
        __syncthreads();
    }

#pragma unroll
    for (int rt = 0; rt < 4; ++rt) {
        float m[4];
#pragma unroll
        for (int reg = 0; reg < 4; ++reg) {
            float mm = acc[rt][0][reg];
#pragma unroll
            for (int ct = 1; ct < 4; ++ct) mm = fmaxf(mm, acc[rt][ct][reg]);
            m[reg] = mm;
        }
#pragma unroll
        for (int off = 1; off < 16; off <<= 1)
#pragma unroll
            for (int reg = 0; reg < 4; ++reg) m[reg] = fmaxf(m[reg], __shfl_xor(m[reg], off));
        if (l15 == 0) {
#pragma unroll
            for (int reg = 0; reg < 4; ++reg)
                redbuf[wc][wr * 64 + rt * 16 + quad * 4 + reg] = m[reg];
        }
    }
    __syncthreads();

    double part = 0.0;
    if (tid < 128) part = (double)fmaxf(redbuf[0][tid], redbuf[1][tid]);
#pragma unroll
    for (int off = 1; off < 64; off <<= 1) part += __shfl_xor(part, off);
    if (lane == 0 && w < 2) red2[w] = part;
    __syncthreads();
    if (tid == 0) scores[(b * NCHUNK + i) * NCHUNK + j] = (float)(red2[0] + red2[1]);
}

// ---------------------------------------------------------------------------
// Stage C: top-7 selection + weights (tiny, serial) — unchanged
// ---------------------------------------------------------------------------
__global__ void topk_kernel(const float* __restrict__ scores,
                            int* __restrict__ ext_idx,
                            float* __restrict__ ext_w) {
    int tid = threadIdx.x;
    if (tid >= NBATCH * NCHUNK) return;
    int b = tid >> 6, i = tid & 63;
    const float* srow = scores + (b * NCHUNK + i) * NCHUNK;

    int nsel = i < KSEL ? i : KSEL;
    float vals[KSEL];
    int   idxs[KSEL];
    unsigned long long used = 0ull;
    for (int s = 0; s < nsel; ++s) {
        float best = -3.0e38f;
        int   bj = 0;
        for (int jj = 0; jj < i; ++jj) {
            if ((used >> jj) & 1ull) continue;
            float v = srow[jj];
            if (v > best) { best = v; bj = jj; }
        }
        used |= 1ull << bj;
        vals[s] = best;
        idxs[s] = bj;
    }
    float vmin = (nsel > 0) ? vals[nsel - 1] : 0.0f;
    float inv  = 1.0f / (vmin + 1e-6f);
    int shift  = KSEL - nsel;
    for (int s = 0; s < KSEL; ++s) {
        int t = s - shift;
        int o = (b * NCHUNK + i) * KSEL + s;
        if (t >= 0) { ext_idx[o] = idxs[t]; ext_w[o] = vals[t] * inv; }
        else        { ext_idx[o] = -1;      ext_w[o] = 0.0f; }
    }
}

// ---------------------------------------------------------------------------
// Stage D: out = dp @ ext + chunk via split-bf16 MFMA with per-slot partials:
//   out = sum_s w_s * (dp[:, s*128:(s+1)*128] @ x_chunk[jj_s])
// accP accumulates the slot's unweighted product; at slot end
// accT += w_s * accP (fp32 VALU). Both operands precomputed bf16 hi/lo,
// staged via global_load_lds. Block = 128 C-rows x 128 E-cols, grid(eh,n,b).
// ---------------------------------------------------------------------------
__global__ __launch_bounds__(256) void out_mfma(const float* __restrict__ x,
                                                const short* __restrict__ dph,
                                                const short* __restrict__ dpl,
                                                const short* __restrict__ xth,
                                                const short* __restrict__ xtl,
                                                const int* __restrict__ ext_idx,
                                                const float* __restrict__ ext_w,
                                                float* __restrict__ out) {
    __shared__ short tiles[4][128 * 32];   // 0=Ahi(dp) 1=Alo 2=Bhi(xT) 3=Blo
    __shared__ int   sjj[8];
    __shared__ float sww[8];

    const int eh = blockIdx.x, n = blockIdx.y, b = blockIdx.z;
    const int e0 = eh * 128;
    const int tid  = threadIdx.x;
    const int w    = tid >> 6, lane = tid & 63;
    const int wr   = w >> 1, wc = w & 1;
    const int quad = lane >> 4, l15 = lane & 15;
    const int rr   = lane >> 2;
    const int c16  = (lane & 3) * 8;

    if (tid < KSEL) {
        sjj[tid] = ext_idx[(b * NCHUNK + n) * KSEL + tid];
        sww[tid] = ext_w [(b * NCHUNK + n) * KSEL + tid];
    }
    if (tid == KSEL) { sjj[KSEL] = n; sww[KSEL] = 1.0f; }
    __syncthreads();

    // staging role: wave w loads matrix w. A source rows: dp rows c (stride
    // LEXT); B source rows: xT rows e (stride TLEN), t-slice of chunk jj.
    const short* adp = (w == 0) ? dph : dpl;                 // waves 0,1
    const short* bxt = (w == 2) ? xth : xtl;                 // waves 2,3
    const short* bbase = bxt + ((size_t)(b * EDIM + e0) * TLEN) + c16;

    floatx4 accT[4][4];
#pragma unroll
    for (int rt = 0; rt < 4; ++rt)
#pragma unroll
        for (int ct = 0; ct < 4; ++ct) accT[rt][ct] = (floatx4){0.f, 0.f, 0.f, 0.f};

    for (int s = 0; s < 8; ++s) {
        const int   jj = sjj[s];
        const float ws = sww[s];
        if (jj < 0) continue;   // block-uniform skip

        floatx4 accP[4][4];
#pragma unroll
        for (int rt = 0; rt < 4; ++rt)
#pragma unroll
            for (int ct = 0; ct < 4; ++ct) accP[rt][ct] = (floatx4){0.f, 0.f, 0.f, 0.f};

        for (int kk = 0; kk < 4; ++kk) {
            short* ldst = &tiles[w][0];
            if (w < 2) {   // A: dp[c][s*128 + kk*32 .. +32]
                const short* gsrc = adp + (size_t)(s * 128 + kk * 32) + c16;
#pragma unroll
                for (int t = 0; t < 8; ++t)
                    gl_lds16(gsrc + (size_t)(16 * t + rr) * LEXT, ldst + t * 512);
            } else {       // B: xT[e][jj*128 + kk*32 .. +32]
                const short* gsrc = bbase + (size_t)(jj * CS + kk * 32);
#pragma unroll
                for (int t = 0; t < 8; ++t)
                    gl_lds16(gsrc + (size_t)(16 * t + rr) * TLEN, ldst + t * 512);
            }
            __syncthreads();

            short8 bh[4], bl[4];
#pragma unroll
            for (int ct = 0; ct < 4; ++ct) {
                int r = wc * 64 + ct * 16 + l15;
                bh[ct] = *(const short8*)&tiles[2][r * 32 + quad * 8];
                bl[ct] = *(const short8*)&tiles[3][r * 32 + quad * 8];
            }
#pragma unroll
            for (int rt = 0; rt < 4; ++rt) {
                int r = wr * 64 + rt * 16 + l15;
                short8 ah = *(const short8*)&tiles[0][r * 32 + quad * 8];
                short8 al = *(const short8*)&tiles[1][r * 32 + quad * 8];
#pragma unroll
                for (int ct = 0; ct < 4; ++ct) {
                    accP[rt][ct] = __builtin_amdgcn_mfma_f32_16x16x32_bf16(ah, bh[ct], accP[rt][ct], 0, 0, 0);
                    accP[rt][ct] = __builtin_amdgcn_mfma_f32_16x16x32_bf16(ah, bl[ct], accP[rt][ct], 0, 0, 0);
                    accP[rt][ct] = __builtin_amdgcn_mfma_f32_16x16x32_bf16(al, bh[ct], accP[rt][ct], 0, 0, 0);
                }
            }
            __syncthreads();
        }
#pragma unroll
        for (int rt = 0; rt < 4; ++rt)
#pragma unroll
            for (int ct = 0; ct < 4; ++ct)
#pragma unroll
                for (int reg = 0; reg < 4; ++reg)
                    accT[rt][ct][reg] += ws * accP[rt][ct][reg];
    }

    // epilogue: D[row = wr*64+rt*16+quad*4+reg][col = wc*64+ct*16+l15] + chunk
#pragma unroll
    for (int rt = 0; rt < 4; ++rt)
#pragma unroll
        for (int ct = 0; ct < 4; ++ct) {
#pragma unroll
            for (int reg = 0; reg < 4; ++reg) {
                int row = wr * 64 + rt * 16 + quad * 4 + reg;
                int col = wc * 64 + ct * 16 + l15;
                size_t o = ((size_t)(b * TLEN + n * CS + row)) * EDIM + e0 + col;
                out[o] = accT[rt][ct][reg] + x[o];
            }
        }
}

// ---------------------------------------------------------------------------
extern "C" void kernel_launch(void* const* d_in, const int* in_sizes, int n_in,
                              void* d_out, int out_size, void* d_ws, size_t ws_size,
                              hipStream_t stream) {
    const float* x  = (const float*)d_in[0];   // [2, 8192, 256] fp32
    const float* dp = (const float*)d_in[1];   // [128, 1024] fp32
    float* out = (float*)d_out;

    char* ws = (char*)d_ws;
    short* cn_hi  = (short*)(ws);                       // 8 MB
    short* cn_lo  = (short*)(ws + (8u << 20));          // 8 MB
    short* xt_hi  = (short*)(ws + (16u << 20));         // 8 MB
    short* xt_lo  = (short*)(ws + (24u << 20));         // 8 MB
    short* dp_hi  = (short*)(ws + (32u << 20));         // 256 KB
    short* dp_lo  = (short*)(ws + (32u << 20) + 262144);
    float* scores = (float*)(ws + (33u << 20));         // 32 KB
    int*   ext_idx = (int*)  (ws + (33u << 20) + 32768);
    float* ext_w   = (float*)(ws + (33u << 20) + 32768 + 4096);

    normsplit_kernel<<<dim3(NBATCH * TLEN / 4), 256, 0, stream>>>(x, cn_hi, cn_lo);
    xt_split_kernel <<<dim3(EDIM / 64, TLEN / 64, NBATCH), 256, 0, stream>>>(x, xt_hi, xt_lo);
    dp_split_kernel <<<dim3(CS * LEXT / 1024), 256, 0, stream>>>(dp, dp_hi, dp_lo);
    scores_mfma     <<<dim3(NCHUNK * (NCHUNK - 1) / 2, NBATCH), 256, 0, stream>>>(cn_hi, cn_lo, scores);
    topk_kernel     <<<1, 128, 0, stream>>>(scores, ext_idx, ext_w);
    out_mfma        <<<dim3(2, NCHUNK, NBATCH), 256, 0, stream>>>(x, dp_hi, dp_lo, xt_hi, xt_lo,
                                                                  ext_idx, ext_w, out);
}